// Round 13
// baseline (1441.168 us; speedup 1.0000x reference)
//
#include <hip/hip_runtime.h>
#include <hip/hip_bf16.h>
#include <stdint.h>

#define E_N 16
#define TOPK 4
#define DD 2560
#define FF 1664
#define FSS 3328
#define TT 2048

typedef __attribute__((ext_vector_type(8))) __bf16 bf16x8;
typedef __attribute__((ext_vector_type(4))) float f32x4;

__device__ __forceinline__ unsigned short f2bf(float f) {
  return __builtin_bit_cast(unsigned short, (__bf16)f);
}
__device__ __forceinline__ unsigned int pk2(float a, float b) {
  return (unsigned int)f2bf(a) | ((unsigned int)f2bf(b) << 16);
}

#define GLOAD16(g, l)                                                          \
  __builtin_amdgcn_global_load_lds(                                            \
      (const __attribute__((address_space(1))) void*)(g),                      \
      (__attribute__((address_space(3))) void*)(l), 16, 0, 0)

#define SBAR() __builtin_amdgcn_s_barrier()
#define VMW(N) asm volatile("s_waitcnt vmcnt(" #N ")" ::: "memory")
#define LGKM0() asm volatile("s_waitcnt lgkmcnt(0)" ::: "memory")

// swizzled block decompose: XCD-chunked bijective remap (requires nwg%8==0)
__device__ __forceinline__ void swz_block(int& bm, int& bn, int& bz) {
  int gx = gridDim.x, gy = gridDim.y;
  int nwg = gx * gy * gridDim.z;
  int flat = blockIdx.x + gx * (blockIdx.y + gy * blockIdx.z);
  if ((nwg & 7) == 0) flat = (flat & 7) * (nwg >> 3) + (flat >> 3);
  bm = flat % gx;
  int rest = flat / gx;
  bn = rest % gy;
  bz = rest / gy;
}

// ---------------- X -> bf16 ----------------
__global__ __launch_bounds__(256) void cvt_bf16_kernel(const float* __restrict__ in,
                                                       unsigned short* __restrict__ out) {
  size_t i = ((size_t)blockIdx.x * 256 + threadIdx.x) * 4;
  float4 v = *reinterpret_cast<const float4*>(in + i);
  ushort4 o;
  o.x = f2bf(v.x); o.y = f2bf(v.y); o.z = f2bf(v.z); o.w = f2bf(v.w);
  *reinterpret_cast<ushort4*>(out + i) = o;
}

// ---------------- weight transpose+convert: [K][N] f32 -> [N][K] bf16 ----------------
__global__ __launch_bounds__(256) void tcvt_kernel(const float* __restrict__ in,
                                                   unsigned short* __restrict__ out,
                                                   int K, int N) {
  __shared__ float lds[64 * 65];
  int z = blockIdx.z;
  in += (size_t)z * K * N;
  out += (size_t)z * K * N;
  int k0 = blockIdx.x * 64, n0 = blockIdx.y * 64;
  int t = threadIdx.x;
#pragma unroll
  for (int j = 0; j < 4; ++j) {
    int idx = j * 256 + t;
    int r = idx >> 4, c = (idx & 15) * 4;
    float4 v = *reinterpret_cast<const float4*>(in + (size_t)(k0 + r) * N + n0 + c);
    lds[r * 65 + c] = v.x;
    lds[r * 65 + c + 1] = v.y;
    lds[r * 65 + c + 2] = v.z;
    lds[r * 65 + c + 3] = v.w;
  }
  __syncthreads();
#pragma unroll
  for (int j = 0; j < 2; ++j) {
    int idx = j * 256 + t;
    int n = idx >> 3, kg = (idx & 7) * 8;
    float a0 = lds[(kg + 0) * 65 + n], a1 = lds[(kg + 1) * 65 + n];
    float a2 = lds[(kg + 2) * 65 + n], a3 = lds[(kg + 3) * 65 + n];
    float a4 = lds[(kg + 4) * 65 + n], a5 = lds[(kg + 5) * 65 + n];
    float a6 = lds[(kg + 6) * 65 + n], a7 = lds[(kg + 7) * 65 + n];
    uint4 o{pk2(a0, a1), pk2(a2, a3), pk2(a4, a5), pk2(a6, a7)};
    *reinterpret_cast<uint4*>(out + (size_t)(n0 + n) * K + k0 + kg) = o;
  }
}

// ---------------- Router ----------------
__global__ __launch_bounds__(256) void router_kernel(const float* __restrict__ x,
                                                     const float* __restrict__ rw,
                                                     int* __restrict__ cnt,
                                                     int* __restrict__ list,
                                                     float* __restrict__ tw) {
  int t = blockIdx.x;
  const float* xr = x + (size_t)t * DD;
  __shared__ float logits[E_N];
  int lane = threadIdx.x & 63, wid = threadIdx.x >> 6;
  for (int ee = 0; ee < 4; ++ee) {
    int e = wid * 4 + ee;
    const float* wr = rw + (size_t)e * DD;
    float p = 0.f;
    for (int d = lane; d < DD; d += 64) p += xr[d] * wr[d];
#pragma unroll
    for (int off = 32; off > 0; off >>= 1) p += __shfl_down(p, off);
    if (lane == 0) logits[e] = p;
  }
  __syncthreads();
  if (threadIdx.x == 0) {
    float mx = -1e30f;
    for (int e = 0; e < E_N; ++e) mx = fmaxf(mx, logits[e]);
    float pe[E_N];
    for (int e = 0; e < E_N; ++e) pe[e] = __expf(logits[e] - mx);
    int idx[TOPK]; float val[TOPK]; float s4 = 0.f;
    unsigned used = 0;
    for (int k = 0; k < TOPK; ++k) {
      int bi = 0; float bv = -1.f;
      for (int e = 0; e < E_N; ++e)
        if (!((used >> e) & 1) && pe[e] > bv) { bv = pe[e]; bi = e; }
      used |= 1u << bi; idx[k] = bi; val[k] = bv; s4 += bv;
    }
    float inv = 1.f / s4;
    for (int k = 0; k < TOPK; ++k) {
      int e2 = idx[k];
      int pos = atomicAdd(&cnt[e2], 1);
      list[e2 * TT + pos] = t * 4 + k;
      tw[t * 4 + k] = val[k] * inv;
    }
  }
}

// ======== fused gate+up GEMM: 256m x (128G|128U stacked B), BK=32, ring-4 ========
// 512 thr / 8 waves (2M x 4N'); per-wave: 128 rows x 32 H-cols, G-frags nf0,1 + U-frags nf2,3.
// ring-4 LDS (4 x 32KB = 128KB), distance-3 prefetch, counted VMW(8), 1 raw barrier/tile.
__global__ __launch_bounds__(512, 1) void guF_kernel(
    const unsigned short* __restrict__ Xb,
    const unsigned short* __restrict__ WgT, const unsigned short* __restrict__ WuT,
    const unsigned short* __restrict__ SgT, const unsigned short* __restrict__ SuT,
    unsigned short* __restrict__ Hx, unsigned short* __restrict__ Hs,
    const int* __restrict__ list, const int* __restrict__ cnt) {
  int bm, bn, z;
  swz_block(bm, bn, z);
  const unsigned short *G0, *U0;
  unsigned short* O0;
  const int* lst = nullptr;
  int M, Nt;
  if (z < E_N) {
    M = cnt[z]; lst = list + z * TT; Nt = FF;
    G0 = WgT + (size_t)z * DD * FF; U0 = WuT + (size_t)z * DD * FF; O0 = Hx;
  } else {
    M = TT; Nt = FSS; G0 = SgT; U0 = SuT; O0 = Hs;
  }
  int m0 = bm * 256, n0 = bn * 128;
  if (m0 >= M || n0 >= Nt) return;

  __shared__ __align__(16) unsigned short lds[4][16384];

  int tid = threadIdx.x, lane = tid & 63, w = tid >> 6;
  int wm = w >> 2, wn = w & 3;

  // staging pointers (source chunk pre-swizzled, LDS dest linear)
  const unsigned short* pA[2];
  const unsigned short* pB[2];
#pragma unroll
  for (int j = 0; j < 2; ++j) {
    int id = j * 512 + tid;
    int row = id >> 2, c = id & 3;
    int cs = c ^ ((row >> 1) & 3);
    int ar = min(m0 + row, M - 1);
    int code = lst ? lst[ar] : ar;
    int tok = lst ? (code >> 2) : code;
    pA[j] = Xb + (size_t)tok * DD + cs * 8;
    pB[j] = (row < 128) ? (G0 + (size_t)(n0 + row) * DD + cs * 8)
                        : (U0 + (size_t)(n0 + row - 128) * DD + cs * 8);
  }

  auto stage = [&](int kt) {
    unsigned short* d = &lds[kt & 3][0];
    int ko = kt * 32;
#pragma unroll
    for (int j = 0; j < 2; ++j) {
      GLOAD16(pA[j] + ko, d + (j * 512 + tid) * 8);
      GLOAD16(pB[j] + ko, d + 8192 + (j * 512 + tid) * 8);
    }
  };

  int cg = lane >> 4;
  int aoff[8], boff[4];
#pragma unroll
  for (int mf = 0; mf < 8; ++mf) {
    int r = wm * 128 + mf * 16 + (lane & 15);
    aoff[mf] = r * 32 + ((cg ^ ((r >> 1) & 3)) * 8);
  }
#pragma unroll
  for (int nf = 0; nf < 4; ++nf) {
    int r = (nf < 2 ? 0 : 128) + wn * 32 + (nf & 1) * 16 + (lane & 15);
    boff[nf] = 8192 + r * 32 + ((cg ^ ((r >> 1) & 3)) * 8);
  }

  f32x4 acc[8][4] = {};

  int nk = DD / 32;
  stage(0); stage(1); stage(2);
  for (int kt = 0; kt < nk; ++kt) {
    int rem = nk - 1 - kt;
    if (rem >= 2) { VMW(8); } else if (rem == 1) { VMW(4); } else { VMW(0); }
    LGKM0();   // all prior ds_reads retired -> safe to overwrite buf (kt-1)&3
    SBAR();    // every wave's tile-kt stages landed; buf (kt-1)&3 free
    if (kt + 3 < nk) stage(kt + 3);
    const unsigned short* L = &lds[kt & 3][0];
    bf16x8 a[8], b[4];
#pragma unroll
    for (int nf = 0; nf < 4; ++nf)
      b[nf] = __builtin_bit_cast(bf16x8, *reinterpret_cast<const uint4*>(L + boff[nf]));
#pragma unroll
    for (int mf = 0; mf < 8; ++mf)
      a[mf] = __builtin_bit_cast(bf16x8, *reinterpret_cast<const uint4*>(L + aoff[mf]));
    __builtin_amdgcn_s_setprio(1);
#pragma unroll
    for (int mf = 0; mf < 8; ++mf)
#pragma unroll
      for (int nf = 0; nf < 4; ++nf)
        acc[mf][nf] = __builtin_amdgcn_mfma_f32_16x16x32_bf16(a[mf], b[nf], acc[mf][nf], 0, 0, 0);
    __builtin_amdgcn_s_setprio(0);
  }

  // epilogue: h = silu(g)*u  (G frags nf0,1 pair with U frags nf2,3 at same cols)
#pragma unroll
  for (int mf = 0; mf < 8; ++mf) {
#pragma unroll
    for (int q = 0; q < 4; ++q) {
      int grow = m0 + wm * 128 + mf * 16 + (lane >> 4) * 4 + q;
      if (grow < M) {
        int code = lst ? lst[grow] : grow;
        unsigned short* Op = O0 + (size_t)code * Nt + n0 + wn * 32 + (lane & 15);
#pragma unroll
        for (int j = 0; j < 2; ++j) {
          float g = acc[mf][j][q], u = acc[mf][2 + j][q];
          Op[j * 16] = f2bf((g / (1.f + __expf(-g))) * u);
        }
      }
    }
  }
}

// ======== down GEMM: 256x256, BK=32, ring-4, distance-3 (same schedule) ========
__global__ __launch_bounds__(512, 1) void dnF_kernel(
    const unsigned short* __restrict__ Hx, const unsigned short* __restrict__ Hs,
    const unsigned short* __restrict__ WdT, const unsigned short* __restrict__ SdT,
    float* __restrict__ Y, float* __restrict__ Ys,
    const int* __restrict__ list, const int* __restrict__ cnt,
    const float* __restrict__ tw) {
  int bm, bn, z;
  swz_block(bm, bn, z);
  const unsigned short* A0;
  const unsigned short* W0;
  float* O0;
  const int* lst = nullptr;
  const float* sc = nullptr;
  int M, Kt;
  if (z < E_N) {
    M = cnt[z]; lst = list + z * TT; Kt = FF;
    A0 = Hx; W0 = WdT + (size_t)z * FF * DD; O0 = Y; sc = tw;
  } else {
    M = TT; Kt = FSS; A0 = Hs; W0 = SdT; O0 = Ys;
  }
  int m0 = bm * 256, n0 = bn * 256;
  if (m0 >= M) return;

  __shared__ __align__(16) unsigned short lds[4][16384];

  int tid = threadIdx.x, lane = tid & 63, w = tid >> 6;
  int wm = w >> 2, wn = w & 3;

  const unsigned short* pA[2];
  const unsigned short* pB[2];
#pragma unroll
  for (int j = 0; j < 2; ++j) {
    int id = j * 512 + tid;
    int row = id >> 2, c = id & 3;
    int cs = c ^ ((row >> 1) & 3);
    int ar = min(m0 + row, M - 1);
    int code = lst ? lst[ar] : ar;
    pA[j] = A0 + (size_t)code * Kt + cs * 8;
    pB[j] = W0 + (size_t)(n0 + row) * Kt + cs * 8;
  }

  auto stage = [&](int kt) {
    unsigned short* d = &lds[kt & 3][0];
    int ko = kt * 32;
#pragma unroll
    for (int j = 0; j < 2; ++j) {
      GLOAD16(pA[j] + ko, d + (j * 512 + tid) * 8);
      GLOAD16(pB[j] + ko, d + 8192 + (j * 512 + tid) * 8);
    }
  };

  int cg = lane >> 4;
  int aoff[8], boff[4];
#pragma unroll
  for (int mf = 0; mf < 8; ++mf) {
    int r = wm * 128 + mf * 16 + (lane & 15);
    aoff[mf] = r * 32 + ((cg ^ ((r >> 1) & 3)) * 8);
  }
#pragma unroll
  for (int nf = 0; nf < 4; ++nf) {
    int r = wn * 64 + nf * 16 + (lane & 15);
    boff[nf] = 8192 + r * 32 + ((cg ^ ((r >> 1) & 3)) * 8);
  }

  f32x4 acc[8][4] = {};

  int nk = Kt / 32;
  stage(0); stage(1); stage(2);
  for (int kt = 0; kt < nk; ++kt) {
    int rem = nk - 1 - kt;
    if (rem >= 2) { VMW(8); } else if (rem == 1) { VMW(4); } else { VMW(0); }
    LGKM0();
    SBAR();
    if (kt + 3 < nk) stage(kt + 3);
    const unsigned short* L = &lds[kt & 3][0];
    bf16x8 a[8], b[4];
#pragma unroll
    for (int nf = 0; nf < 4; ++nf)
      b[nf] = __builtin_bit_cast(bf16x8, *reinterpret_cast<const uint4*>(L + boff[nf]));
#pragma unroll
    for (int mf = 0; mf < 8; ++mf)
      a[mf] = __builtin_bit_cast(bf16x8, *reinterpret_cast<const uint4*>(L + aoff[mf]));
    __builtin_amdgcn_s_setprio(1);
#pragma unroll
    for (int mf = 0; mf < 8; ++mf)
#pragma unroll
      for (int nf = 0; nf < 4; ++nf)
        acc[mf][nf] = __builtin_amdgcn_mfma_f32_16x16x32_bf16(a[mf], b[nf], acc[mf][nf], 0, 0, 0);
    __builtin_amdgcn_s_setprio(0);
  }

#pragma unroll
  for (int mf = 0; mf < 8; ++mf) {
#pragma unroll
    for (int q = 0; q < 4; ++q) {
      int grow = m0 + wm * 128 + mf * 16 + (lane >> 4) * 4 + q;
      if (grow < M) {
        int code = lst ? lst[grow] : grow;
        float scale = sc ? sc[code] : 1.f;
        float* Op = O0 + (size_t)code * DD + n0 + wn * 64 + (lane & 15);
#pragma unroll
        for (int nf = 0; nf < 4; ++nf) Op[nf * 16] = acc[mf][nf][q] * scale;
      }
    }
  }
}

// ---------------- combine ----------------
__global__ __launch_bounds__(256) void combine_kernel(const float* __restrict__ Y,
                                                      const float* __restrict__ Ys,
                                                      float* __restrict__ out) {
  size_t i = ((size_t)blockIdx.x * 256 + threadIdx.x) * 4;
  size_t t = i / DD;
  int d = (int)(i % DD);
  float4 a = *reinterpret_cast<const float4*>(Ys + i);
#pragma unroll
  for (int k = 0; k < 4; ++k) {
    float4 v = *reinterpret_cast<const float4*>(Y + (t * 4 + k) * (size_t)DD + d);
    a.x += v.x; a.y += v.y; a.z += v.z; a.w += v.w;
  }
  *reinterpret_cast<float4*>(out + i) = a;
}

extern "C" void kernel_launch(void* const* d_in, const int* in_sizes, int n_in,
                              void* d_out, int out_size, void* d_ws, size_t ws_size,
                              hipStream_t stream) {
  const float* x  = (const float*)d_in[0];
  const float* rw = (const float*)d_in[1];
  const float* wg = (const float*)d_in[2];
  const float* wu = (const float*)d_in[3];
  const float* wd = (const float*)d_in[4];
  const float* sg = (const float*)d_in[5];
  const float* su = (const float*)d_in[6];
  const float* sd = (const float*)d_in[7];
  float* out = (float*)d_out;

  char* ws = (char*)d_ws;
  size_t off = 0;
  auto alloc = [&](size_t bytes) {
    off = (off + 255) & ~(size_t)255;
    void* p = ws + off;
    off += bytes;
    return p;
  };
  unsigned short* W1 = (unsigned short*)alloc((size_t)E_N * FF * DD * 2);   // 136 MB
  unsigned short* W2 = (unsigned short*)alloc((size_t)E_N * FF * DD * 2);   // 136 MB
  unsigned short* W3 = (unsigned short*)alloc((size_t)FSS * DD * 2);        // 17 MB
  unsigned short* W4 = (unsigned short*)alloc((size_t)FSS * DD * 2);        // 17 MB
  unsigned short* Xb = (unsigned short*)alloc((size_t)TT * DD * 2);
  unsigned short* Hx = (unsigned short*)alloc((size_t)4 * TT * FF * 2);
  unsigned short* Hs = (unsigned short*)alloc((size_t)TT * FSS * 2);
  float* Y  = (float*)alloc((size_t)4 * TT * DD * 4);
  float* Ys = (float*)alloc((size_t)TT * DD * 4);
  float* tw = (float*)alloc((size_t)4 * TT * 4);
  int* cnt  = (int*)alloc(E_N * 4);
  int* list = (int*)alloc((size_t)E_N * TT * 4);
  (void)ws_size; (void)in_sizes; (void)n_in; (void)out_size;

  hipMemsetAsync(cnt, 0, E_N * 4, stream);
  cvt_bf16_kernel<<<TT * DD / 4 / 256, 256, 0, stream>>>(x, Xb);
  router_kernel<<<TT, 256, 0, stream>>>(x, rw, cnt, list, tw);

  // --- gate/up weight transposes: [D][F(S)] -> [F(S)][D] bf16 ---
  tcvt_kernel<<<dim3(DD / 64, FF / 64, E_N), 256, 0, stream>>>(wg, W1, DD, FF);
  tcvt_kernel<<<dim3(DD / 64, FF / 64, E_N), 256, 0, stream>>>(wu, W2, DD, FF);
  tcvt_kernel<<<dim3(DD / 64, FSS / 64, 1), 256, 0, stream>>>(sg, W3, DD, FSS);
  tcvt_kernel<<<dim3(DD / 64, FSS / 64, 1), 256, 0, stream>>>(su, W4, DD, FSS);

  // --- fused gate+up (z: 16 experts + 1 shared), silu in-epilogue ---
  guF_kernel<<<dim3(TT * 4 / 256, FSS / 128, E_N + 1), 512, 0, stream>>>(
      Xb, W1, W2, W3, W4, Hx, Hs, list, cnt);

  // --- down weight transposes (reuse W1/W2) ---
  tcvt_kernel<<<dim3(FF / 64, DD / 64, E_N), 256, 0, stream>>>(wd, W1, FF, DD);
  tcvt_kernel<<<dim3(FSS / 64, DD / 64, 1), 256, 0, stream>>>(sd, W2, FSS, DD);

  // --- down GEMMs (z: 16 experts + 1 shared) ---
  dnF_kernel<<<dim3(TT * 4 / 256, DD / 256, E_N + 1), 512, 0, stream>>>(
      Hx, Hs, W1, W2, Y, Ys, list, cnt, tw);

  combine_kernel<<<TT * DD / 4 / 256, 256, 0, stream>>>(Y, Ys, out);
}

// Round 14
// 1334.431 us; speedup vs baseline: 1.0800x; 1.0800x over previous
//
#include <hip/hip_runtime.h>
#include <hip/hip_bf16.h>
#include <stdint.h>

#define E_N 16
#define TOPK 4
#define DD 2560
#define FF 1664
#define FSS 3328
#define TT 2048
#define BK 32

typedef __attribute__((ext_vector_type(8))) __bf16 bf16x8;
typedef __attribute__((ext_vector_type(4))) float f32x4;

__device__ __forceinline__ unsigned short f2bf(float f) {
  return __builtin_bit_cast(unsigned short, (__bf16)f);
}
__device__ __forceinline__ unsigned int pk2(float a, float b) {
  return (unsigned int)f2bf(a) | ((unsigned int)f2bf(b) << 16);
}

#define GLOAD16(g, l)                                                          \
  __builtin_amdgcn_global_load_lds(                                            \
      (const __attribute__((address_space(1))) void*)(g),                      \
      (__attribute__((address_space(3))) void*)(l), 16, 0, 0)

#define SBAR() __builtin_amdgcn_s_barrier()
#define SCHED0() __builtin_amdgcn_sched_barrier(0)
#define VMW(N) asm volatile("s_waitcnt vmcnt(" #N ")" ::: "memory")

// ---- P1 block ranges ----
#define NB_TGW 16640            // wg tcvt: 40x26x16
#define NB_TGU 16640            // wu tcvt
#define NB_TSG 2080             // sg tcvt: 40x52
#define NB_TSU 2080             // su tcvt
#define NB_CVT 5120             // x->bf16
#define NB_RTR 2048             // router
#define NB_P1 (NB_TGW + NB_TGU + NB_TSG + NB_TSU + NB_CVT + NB_RTR)  // 44608

// ---- P2 block ranges ----
#define NB_GUE 3328             // 16 experts x (13 bn x 16 bm)
#define NB_GUS 416              // shared: 26 bn x 16 bm
#define NB_GU (NB_GUE + NB_GUS) // 3744 (%8==0)
#define NB_TWD 16640            // wd tcvt: 26x40x16
#define NB_TSD 2080             // sd tcvt: 52x40
#define NB_P2 (NB_GU + NB_TWD + NB_TSD)  // 22464

// ---- P3 block ranges ----
#define NB_DNE 5120             // 16 experts x (20 bn x 16 bm)
#define NB_DNS 320              // shared
#define NB_DN (NB_DNE + NB_DNS) // 5440 (%8==0)

// =================== weight transpose+convert body ===================
// [K][N] f32 -> [N][K] bf16, 64x64 tile at (k0,n0); lds = float[64*65]
__device__ __forceinline__ void tcvt_body(const float* __restrict__ in,
                                          unsigned short* __restrict__ out,
                                          int K, int N, int k0, int n0, float* lds) {
  int t = threadIdx.x;
#pragma unroll
  for (int j = 0; j < 4; ++j) {
    int idx = j * 256 + t;
    int r = idx >> 4, c = (idx & 15) * 4;
    float4 v = *reinterpret_cast<const float4*>(in + (size_t)(k0 + r) * N + n0 + c);
    lds[r * 65 + c] = v.x;
    lds[r * 65 + c + 1] = v.y;
    lds[r * 65 + c + 2] = v.z;
    lds[r * 65 + c + 3] = v.w;
  }
  __syncthreads();
#pragma unroll
  for (int j = 0; j < 2; ++j) {
    int idx = j * 256 + t;
    int n = idx >> 3, kg = (idx & 7) * 8;
    float a0 = lds[(kg + 0) * 65 + n], a1 = lds[(kg + 1) * 65 + n];
    float a2 = lds[(kg + 2) * 65 + n], a3 = lds[(kg + 3) * 65 + n];
    float a4 = lds[(kg + 4) * 65 + n], a5 = lds[(kg + 5) * 65 + n];
    float a6 = lds[(kg + 6) * 65 + n], a7 = lds[(kg + 7) * 65 + n];
    uint4 o{pk2(a0, a1), pk2(a2, a3), pk2(a4, a5), pk2(a6, a7)};
    *reinterpret_cast<uint4*>(out + (size_t)(n0 + n) * K + k0 + kg) = o;
  }
}

// =================== PHASE 1: gate/up tcvt + X cvt + router ===================
__global__ __launch_bounds__(256) void phase1_kernel(
    const float* __restrict__ x, const float* __restrict__ rw,
    const float* __restrict__ wg, const float* __restrict__ wu,
    const float* __restrict__ sg, const float* __restrict__ su,
    unsigned short* __restrict__ Xb,
    unsigned short* __restrict__ W1, unsigned short* __restrict__ W2,
    unsigned short* __restrict__ W3, unsigned short* __restrict__ W4,
    int* __restrict__ cnt, int* __restrict__ list, float* __restrict__ tw) {
  __shared__ __align__(16) unsigned char smem[16640];
  int b = blockIdx.x;
  if (b < NB_TGW) {
    int z = b / 1040, r = b % 1040, bx = r % 40, by = r / 40;
    tcvt_body(wg + (size_t)z * DD * FF, W1 + (size_t)z * DD * FF, DD, FF,
              bx * 64, by * 64, (float*)smem);
    return;
  }
  b -= NB_TGW;
  if (b < NB_TGU) {
    int z = b / 1040, r = b % 1040, bx = r % 40, by = r / 40;
    tcvt_body(wu + (size_t)z * DD * FF, W2 + (size_t)z * DD * FF, DD, FF,
              bx * 64, by * 64, (float*)smem);
    return;
  }
  b -= NB_TGU;
  if (b < NB_TSG) {
    int bx = b % 40, by = b / 40;
    tcvt_body(sg, W3, DD, FSS, bx * 64, by * 64, (float*)smem);
    return;
  }
  b -= NB_TSG;
  if (b < NB_TSU) {
    int bx = b % 40, by = b / 40;
    tcvt_body(su, W4, DD, FSS, bx * 64, by * 64, (float*)smem);
    return;
  }
  b -= NB_TSU;
  if (b < NB_CVT) {
    size_t i = ((size_t)b * 256 + threadIdx.x) * 4;
    float4 v = *reinterpret_cast<const float4*>(x + i);
    ushort4 o;
    o.x = f2bf(v.x); o.y = f2bf(v.y); o.z = f2bf(v.z); o.w = f2bf(v.w);
    *reinterpret_cast<ushort4*>(Xb + i) = o;
    return;
  }
  b -= NB_CVT;
  {  // router, token t = b
    int t = b;
    const float* xr = x + (size_t)t * DD;
    float* logits = (float*)smem;
    int lane = threadIdx.x & 63, wid = threadIdx.x >> 6;
    for (int ee = 0; ee < 4; ++ee) {
      int e = wid * 4 + ee;
      const float* wr = rw + (size_t)e * DD;
      float p = 0.f;
      for (int d = lane; d < DD; d += 64) p += xr[d] * wr[d];
#pragma unroll
      for (int off = 32; off > 0; off >>= 1) p += __shfl_down(p, off);
      if (lane == 0) logits[e] = p;
    }
    __syncthreads();
    if (threadIdx.x == 0) {
      float mx = -1e30f;
      for (int e = 0; e < E_N; ++e) mx = fmaxf(mx, logits[e]);
      float pe[E_N];
      for (int e = 0; e < E_N; ++e) pe[e] = __expf(logits[e] - mx);
      int idx[TOPK]; float val[TOPK]; float s4 = 0.f;
      unsigned used = 0;
      for (int k = 0; k < TOPK; ++k) {
        int bi = 0; float bv = -1.f;
        for (int e = 0; e < E_N; ++e)
          if (!((used >> e) & 1) && pe[e] > bv) { bv = pe[e]; bi = e; }
        used |= 1u << bi; idx[k] = bi; val[k] = bv; s4 += bv;
      }
      float inv = 1.f / s4;
      for (int k = 0; k < TOPK; ++k) {
        int e2 = idx[k];
        int pos = atomicAdd(&cnt[e2], 1);
        list[e2 * TT + pos] = t * 4 + k;
        tw[t * 4 + k] = val[k] * inv;
      }
    }
  }
}

// =================== r6 gu body (proven): 128x128, ring-3, 1 barrier ===================
__device__ __forceinline__ void gu_body(
    const unsigned short* __restrict__ Xb,
    const unsigned short* __restrict__ Bg0, const unsigned short* __restrict__ Bu0,
    unsigned short* __restrict__ H, const int* lst,
    int M, int Ktot, int Ntot, int m0, int n0, unsigned short* ldsbase) {
  int tid = threadIdx.x, lane = tid & 63, w = tid >> 6;

  const unsigned short* pA[2];
#pragma unroll
  for (int q = 0; q < 2; ++q) {
    int J = w * 2 + q;
    int row = J * 16 + (lane >> 2);
    int c = lane & 3;
    int cs = c ^ ((row >> 1) & 3);
    int ar = min(m0 + row, M - 1);
    int tok = lst ? (lst[ar] >> 2) : ar;
    pA[q] = Xb + (size_t)tok * Ktot + cs * 8;
  }
  const unsigned short* pGU[4];
#pragma unroll
  for (int q = 0; q < 4; ++q) {
    int J = w * 4 + q;
    int row = J * 8 + (lane >> 3);
    int c = lane & 7;
    int sc = c ^ (row & 7);
    pGU[q] = (sc < 4) ? (Bg0 + (size_t)(n0 + row) * Ktot + sc * 8)
                      : (Bu0 + (size_t)(n0 + row) * Ktot + (sc - 4) * 8);
  }

  auto issue = [&](int kt, int buf) {
    int koff = kt * BK;
    unsigned short* dA = ldsbase + buf * 12288;
    unsigned short* dGU = dA + 4096;
#pragma unroll
    for (int q = 0; q < 2; ++q)
      GLOAD16(pA[q] + koff, dA + (w * 2 + q) * 512);
#pragma unroll
    for (int q = 0; q < 4; ++q)
      GLOAD16(pGU[q] + koff, dGU + (w * 4 + q) * 512);
  };

  int wr = (w >> 1) * 64, wc = (w & 1) * 64;
  int cg = lane >> 4;
  int aoff[4], goff[4], uoff[4];
#pragma unroll
  for (int m = 0; m < 4; ++m) {
    int r = wr + m * 16 + (lane & 15);
    aoff[m] = r * 32 + ((cg ^ ((r >> 1) & 3)) * 8);
  }
#pragma unroll
  for (int n = 0; n < 4; ++n) {
    int r = wc + n * 16 + (lane & 15);
    goff[n] = r * 64 + ((cg ^ (r & 7)) * 8);
    uoff[n] = r * 64 + (((cg + 4) ^ (r & 7)) * 8);
  }

  f32x4 accG[4][4] = {};
  f32x4 accU[4][4] = {};

  auto compute = [&](int buf) {
    const unsigned short* A = ldsbase + buf * 12288;
    const unsigned short* GU = A + 4096;
    bf16x8 a[4], g[4], u[4];
#pragma unroll
    for (int m = 0; m < 4; ++m)
      a[m] = __builtin_bit_cast(bf16x8, *reinterpret_cast<const uint4*>(A + aoff[m]));
#pragma unroll
    for (int n = 0; n < 4; ++n) {
      g[n] = __builtin_bit_cast(bf16x8, *reinterpret_cast<const uint4*>(GU + goff[n]));
      u[n] = __builtin_bit_cast(bf16x8, *reinterpret_cast<const uint4*>(GU + uoff[n]));
    }
    __builtin_amdgcn_s_setprio(1);
#pragma unroll
    for (int m = 0; m < 4; ++m)
#pragma unroll
      for (int n = 0; n < 4; ++n) {
        accG[m][n] = __builtin_amdgcn_mfma_f32_16x16x32_bf16(a[m], g[n], accG[m][n], 0, 0, 0);
        accU[m][n] = __builtin_amdgcn_mfma_f32_16x16x32_bf16(a[m], u[n], accU[m][n], 0, 0, 0);
      }
    __builtin_amdgcn_s_setprio(0);
  };

  int nk = Ktot / BK;
  issue(0, 0);
  issue(1, 1);
  for (int kt = 0; kt < nk; ++kt) {
    if (kt == nk - 1) { VMW(0); } else { VMW(6); }
    SCHED0();
    SBAR(); SCHED0();
    if (kt + 2 < nk) { issue(kt + 2, (kt + 2) % 3); SCHED0(); }
    compute(kt % 3);
    SCHED0();
  }

#pragma unroll
  for (int m = 0; m < 4; ++m) {
#pragma unroll
    for (int r = 0; r < 4; ++r) {
      int lr = wr + m * 16 + (lane >> 4) * 4 + r;
      int grow = m0 + lr;
      if (grow < M) {
        int code = lst ? lst[grow] : grow;
        unsigned short* Hp = H + (size_t)code * Ntot + n0 + wc + (lane & 15);
#pragma unroll
        for (int n = 0; n < 4; ++n) {
          float gg = accG[m][n][r], uu = accU[m][n][r];
          Hp[n * 16] = f2bf((gg / (1.f + __expf(-gg))) * uu);
        }
      }
    }
  }
}

// =================== PHASE 2: gu GEMM (expert+shared) + down tcvt ===================
__global__ __launch_bounds__(256, 2) void phase2_kernel(
    const unsigned short* __restrict__ Xb,
    const unsigned short* __restrict__ W1, const unsigned short* __restrict__ W2,
    const unsigned short* __restrict__ W3, const unsigned short* __restrict__ W4,
    unsigned short* __restrict__ Hx, unsigned short* __restrict__ Hs,
    const int* __restrict__ list, const int* __restrict__ cnt,
    const float* __restrict__ wd, const float* __restrict__ sd,
    unsigned short* __restrict__ W5, unsigned short* __restrict__ W6) {
  __shared__ __align__(16) unsigned char smem[73728];
  int b = blockIdx.x;
  if (b < NB_GU) {
    // XCD-chunked bijective swizzle within gu range (3744 % 8 == 0)
    int swz = (b & 7) * (NB_GU / 8) + (b >> 3);
    int bm, bn, z;
    if (swz < NB_GUE) { z = swz / 208; int r = swz % 208; bm = r & 15; bn = r >> 4; }
    else { int i = swz - NB_GUE; z = E_N; bm = i & 15; bn = i >> 4; }
    const unsigned short *G0, *U0;
    unsigned short* O0;
    const int* lst = nullptr;
    int M, Nt;
    if (z < E_N) {
      M = cnt[z]; lst = list + z * TT; Nt = FF;
      G0 = W1 + (size_t)z * DD * FF; U0 = W2 + (size_t)z * DD * FF; O0 = Hx;
    } else {
      M = TT; Nt = FSS; G0 = W3; U0 = W4; O0 = Hs;
    }
    int m0 = bm * 128, n0 = bn * 128;
    if (m0 >= M || n0 >= Nt) return;
    gu_body(Xb, G0, U0, O0, lst, M, DD, Nt, m0, n0, (unsigned short*)smem);
    return;
  }
  b -= NB_GU;
  if (b < NB_TWD) {
    int z = b / 1040, r = b % 1040, bx = r % 26, by = r / 26;
    tcvt_body(wd + (size_t)z * FF * DD, W5 + (size_t)z * FF * DD, FF, DD,
              bx * 64, by * 64, (float*)smem);
    return;
  }
  b -= NB_TWD;
  {
    int bx = b % 52, by = b / 52;
    tcvt_body(sd, W6, FSS, DD, bx * 64, by * 64, (float*)smem);
  }
}

// =================== PHASE 3: down GEMM (expert+shared merged) ===================
__global__ __launch_bounds__(256, 3) void phase3_kernel(
    const unsigned short* __restrict__ Hx, const unsigned short* __restrict__ Hs,
    const unsigned short* __restrict__ W5, const unsigned short* __restrict__ W6,
    float* __restrict__ Y, float* __restrict__ Ys,
    const int* __restrict__ list, const int* __restrict__ cnt,
    const float* __restrict__ tw) {
  __shared__ __align__(16) unsigned short lds[3][8192];
  int b = blockIdx.x;
  int swz = (b & 7) * (NB_DN / 8) + (b >> 3);
  int bm, bn, z;
  if (swz < NB_DNE) { z = swz / 320; int r = swz % 320; bm = r & 15; bn = r >> 4; }
  else { int i = swz - NB_DNE; z = E_N; bm = i & 15; bn = i >> 4; }

  const unsigned short* A0;
  const unsigned short* B0;
  float* O0;
  const int* lst = nullptr;
  const float* sc = nullptr;
  int M, Kt;
  if (z < E_N) {
    M = cnt[z]; lst = list + z * TT; Kt = FF;
    A0 = Hx; B0 = W5 + (size_t)z * FF * DD; O0 = Y; sc = tw;
  } else {
    M = TT; Kt = FSS; A0 = Hs; B0 = W6; O0 = Ys;
  }
  int m0 = bm * 128, n0 = bn * 128;
  if (m0 >= M) return;

  int tid = threadIdx.x, lane = tid & 63, w = tid >> 6;

  const unsigned short* pAB[4];
#pragma unroll
  for (int q = 0; q < 4; ++q) {
    int J = w * 4 + q;
    int row = J * 8 + (lane >> 3);
    int c = lane & 7;
    int scx = c ^ (row & 7);
    if (scx < 4) {
      int ar = min(m0 + row, M - 1);
      int code = lst ? lst[ar] : ar;
      pAB[q] = A0 + (size_t)code * Kt + scx * 8;
    } else {
      pAB[q] = B0 + (size_t)(n0 + row) * Kt + (scx - 4) * 8;
    }
  }

  auto issue = [&](int kt, int buf) {
    int koff = kt * BK;
    unsigned short* d = &lds[buf][0];
#pragma unroll
    for (int q = 0; q < 4; ++q)
      GLOAD16(pAB[q] + koff, d + (w * 4 + q) * 512);
  };

  int wr = (w >> 1) * 64, wc = (w & 1) * 64;
  int cg = lane >> 4;
  int aoff[4], boff[4];
#pragma unroll
  for (int m = 0; m < 4; ++m) {
    int r = wr + m * 16 + (lane & 15);
    aoff[m] = r * 64 + ((cg ^ (r & 7)) * 8);
  }
#pragma unroll
  for (int n = 0; n < 4; ++n) {
    int r = wc + n * 16 + (lane & 15);
    boff[n] = r * 64 + (((cg + 4) ^ (r & 7)) * 8);
  }

  f32x4 acc[4][4] = {};

  auto compute = [&](int buf) {
    const unsigned short* AB = &lds[buf][0];
    bf16x8 a[4], bb[4];
#pragma unroll
    for (int m = 0; m < 4; ++m)
      a[m] = __builtin_bit_cast(bf16x8, *reinterpret_cast<const uint4*>(AB + aoff[m]));
#pragma unroll
    for (int n = 0; n < 4; ++n)
      bb[n] = __builtin_bit_cast(bf16x8, *reinterpret_cast<const uint4*>(AB + boff[n]));
    __builtin_amdgcn_s_setprio(1);
#pragma unroll
    for (int m = 0; m < 4; ++m)
#pragma unroll
      for (int n = 0; n < 4; ++n)
        acc[m][n] = __builtin_amdgcn_mfma_f32_16x16x32_bf16(a[m], bb[n], acc[m][n], 0, 0, 0);
    __builtin_amdgcn_s_setprio(0);
  };

  int nk = Kt / BK;
  issue(0, 0);
  issue(1, 1);
  for (int kt = 0; kt < nk; ++kt) {
    if (kt == nk - 1) { VMW(0); } else { VMW(4); }
    SCHED0();
    SBAR(); SCHED0();
    if (kt + 2 < nk) { issue(kt + 2, (kt + 2) % 3); SCHED0(); }
    compute(kt % 3);
    SCHED0();
  }

#pragma unroll
  for (int m = 0; m < 4; ++m) {
#pragma unroll
    for (int r = 0; r < 4; ++r) {
      int lr = wr + m * 16 + (lane >> 4) * 4 + r;
      int grow = m0 + lr;
      if (grow < M) {
        int code = lst ? lst[grow] : grow;
        float scale = sc ? sc[code] : 1.f;
        float* Yp = O0 + (size_t)code * DD + n0 + wc + (lane & 15);
#pragma unroll
        for (int n = 0; n < 4; ++n) Yp[n * 16] = acc[m][n][r] * scale;
      }
    }
  }
}

// ---------------- combine ----------------
__global__ __launch_bounds__(256) void combine_kernel(const float* __restrict__ Y,
                                                      const float* __restrict__ Ys,
                                                      float* __restrict__ out) {
  size_t i = ((size_t)blockIdx.x * 256 + threadIdx.x) * 4;
  size_t t = i / DD;
  int d = (int)(i % DD);
  float4 a = *reinterpret_cast<const float4*>(Ys + i);
#pragma unroll
  for (int k = 0; k < 4; ++k) {
    float4 v = *reinterpret_cast<const float4*>(Y + (t * 4 + k) * (size_t)DD + d);
    a.x += v.x; a.y += v.y; a.z += v.z; a.w += v.w;
  }
  *reinterpret_cast<float4*>(out + i) = a;
}

extern "C" void kernel_launch(void* const* d_in, const int* in_sizes, int n_in,
                              void* d_out, int out_size, void* d_ws, size_t ws_size,
                              hipStream_t stream) {
  const float* x  = (const float*)d_in[0];
  const float* rw = (const float*)d_in[1];
  const float* wg = (const float*)d_in[2];
  const float* wu = (const float*)d_in[3];
  const float* wd = (const float*)d_in[4];
  const float* sg = (const float*)d_in[5];
  const float* su = (const float*)d_in[6];
  const float* sd = (const float*)d_in[7];
  float* out = (float*)d_out;

  char* ws = (char*)d_ws;
  size_t off = 0;
  auto alloc = [&](size_t bytes) {
    off = (off + 255) & ~(size_t)255;
    void* p = ws + off;
    off += bytes;
    return p;
  };
  unsigned short* W1 = (unsigned short*)alloc((size_t)E_N * FF * DD * 2);   // 136 MB (gate)
  unsigned short* W2 = (unsigned short*)alloc((size_t)E_N * FF * DD * 2);   // 136 MB (up)
  unsigned short* W3 = (unsigned short*)alloc((size_t)FSS * DD * 2);        // 17 MB
  unsigned short* W4 = (unsigned short*)alloc((size_t)FSS * DD * 2);        // 17 MB
  unsigned short* W5 = (unsigned short*)alloc((size_t)E_N * FF * DD * 2);   // 136 MB (down)
  unsigned short* W6 = (unsigned short*)alloc((size_t)FSS * DD * 2);        // 17 MB
  unsigned short* Xb = (unsigned short*)alloc((size_t)TT * DD * 2);
  unsigned short* Hx = (unsigned short*)alloc((size_t)4 * TT * FF * 2);
  unsigned short* Hs = (unsigned short*)alloc((size_t)TT * FSS * 2);
  float* tw = (float*)alloc((size_t)4 * TT * 4);
  int* cnt  = (int*)alloc(E_N * 4);
  int* list = (int*)alloc((size_t)E_N * TT * 4);
  // Alias: W1/W2 (gate/up bf16) are dead after phase2; reuse for Y/Ys.
  float* Y  = (float*)W2;   // needs 84 MB <= 136 MB
  float* Ys = (float*)W1;   // needs 21 MB <= 136 MB
  (void)ws_size; (void)in_sizes; (void)n_in; (void)out_size;

  hipMemsetAsync(cnt, 0, E_N * 4, stream);

  // P1: gate/up weight transposes + X->bf16 + router (all independent)
  phase1_kernel<<<NB_P1, 256, 0, stream>>>(x, rw, wg, wu, sg, su,
                                           Xb, W1, W2, W3, W4, cnt, list, tw);

  // P2: fused gate+up GEMM (expert+shared)  ||  down weight transposes (hidden)
  phase2_kernel<<<NB_P2, 256, 0, stream>>>(Xb, W1, W2, W3, W4, Hx, Hs, list, cnt,
                                           wd, sd, W5, W6);

  // P3: down GEMM (expert+shared merged)
  phase3_kernel<<<NB_DN, 256, 0, stream>>>(Hx, Hs, W5, W6, Y, Ys, list, cnt, tw);

  // P4: combine
  combine_kernel<<<TT * DD / 4 / 256, 256, 0, stream>>>(Y, Ys, out);
}